// Round 5
// baseline (616.077 us; speedup 1.0000x reference)
//
#include <hip/hip_runtime.h>
#include <hip/hip_fp16.h>

typedef _Float16 f16;
typedef __attribute__((ext_vector_type(8))) _Float16 f16x8;
typedef __attribute__((ext_vector_type(4))) float f32x4;

#define NPTS 8192
#define DIM  1024
#define HL2E 0.721347520444482f   // log2(e)/2
#define S2SHIFT 50.0f             // store exp((s-50)/2) in f16
#define TBUF (128 * 32)           // one LDS tile buffer (f16 elems)

// async global->LDS, 16B per lane; lds base must be wave-uniform
__device__ __forceinline__ void glds16(const void* g, void* l) {
  __builtin_amdgcn_global_load_lds(
      (const __attribute__((address_space(1))) void*)g,
      (__attribute__((address_space(3))) void*)l, 16, 0, 0);
}

// ---------- small helpers ----------
__global__ void cvt_f32_f16(const float* __restrict__ src, f16* __restrict__ dst, int n) {
  int i = (blockIdx.x * 256 + threadIdx.x) * 8;
  if (i >= n) return;
  const float4* s = (const float4*)(src + i);
  float4 a = s[0], b = s[1];
  f16x8 o;
  o[0] = (f16)a.x; o[1] = (f16)a.y; o[2] = (f16)a.z; o[3] = (f16)a.w;
  o[4] = (f16)b.x; o[5] = (f16)b.y; o[6] = (f16)b.z; o[7] = (f16)b.w;
  *(f16x8*)(dst + i) = o;
}

__global__ void zero_f32(float* __restrict__ p, int n) {
  int i = blockIdx.x * 256 + threadIdx.x;
  if (i < n) p[i] = 0.f;
}

// out = p (residual pre-load; PV splits atomicAdd on top)
__global__ void init_out(const float* __restrict__ p, float* __restrict__ out) {
  long i = ((long)blockIdx.x * 256 + threadIdx.x) * 4;
  *(float4*)(out + i) = *(const float4*)(p + i);
}

// colsum -> ics2 = cs^-1/2 (for v), ics4 = cs^-1/4 (for P staging)
__global__ void mk_scales(const float* __restrict__ colsum,
                          f16* __restrict__ ics2, f16* __restrict__ ics4) {
  int j = blockIdx.x * 256 + threadIdx.x;
  float r2 = rsqrtf(colsum[j]);
  ics2[j] = (f16)r2;
  ics4[j] = (f16)sqrtf(r2);
}

// vt[n][j] *= ics2[j]  (in place, 8-wide packed)
__global__ void vscale(f16* __restrict__ vt, const f16* __restrict__ ics2) {
  long i = ((long)blockIdx.x * 256 + threadIdx.x) * 8;
  f16x8 v = *(f16x8*)(vt + i);
  f16x8 s = *(const f16x8*)(ics2 + (i & (NPTS - 1)));
  *(f16x8*)(vt + i) = v * s;
}

// ---------- fused projections: q = p@Wh^T+bh, k = r@Wl^T+bl, vt = (p@Wg^T+bg)^T ----------
// grid 1536: sub = b>>9 selects projection; b&511 swizzled (bi=b&63 -> XCD round-robin).
// All three GEMMs in ONE launch -> ~5 blocks/CU co-resident (vs 2 at 512) so one
// block's barrier drain is covered by other blocks' MFMA issue.
__global__ __launch_bounds__(256, 2)
void proj_fused(const f16* __restrict__ p_h, const f16* __restrict__ r_h,
                const f16* __restrict__ Wh, const f16* __restrict__ Wl,
                const f16* __restrict__ Wg,
                const float* __restrict__ bh, const float* __restrict__ bl,
                const float* __restrict__ bg,
                f16* __restrict__ q_h, f16* __restrict__ k_h,
                f16* __restrict__ vt_h) {
  __shared__ f16 sA[2 * TBUF];
  __shared__ f16 sB[2 * TBUF];
  const int sub = blockIdx.x >> 9;
  const int bl_ = blockIdx.x & 511;
  const long bi = (long)(bl_ & 63) * 128;
  const long bj = (long)(bl_ >> 6) * 128;
  const f16* A = (sub == 1) ? r_h : p_h;
  const f16* B = (sub == 0) ? Wh : (sub == 1) ? Wl : Wg;
  const float* bias = (sub == 0) ? bh : (sub == 1) ? bl : bg;

  const int t = threadIdx.x;
  const int w = t >> 6, l = t & 63;
  const int wm = (w >> 1) * 64, wn = (w & 1) * 64;
  const int lr = l & 15, lk = (l >> 4) * 8;
  const int grow = w * 16 + (l >> 2);
  const int gcol = (l & 3) * 8;
  const f16* gA = A + (bi + grow) * (long)DIM + gcol;
  const f16* gB = B + (bj + grow) * (long)DIM + gcol;
  const int lw0 = (w * 16) * 32, lw1 = (64 + w * 16) * 32;

  glds16(gA, sA + lw0);
  glds16(gA + 64l * DIM, sA + lw1);
  glds16(gB, sB + lw0);
  glds16(gB + 64l * DIM, sB + lw1);
  gA += 32; gB += 32;

  f32x4 acc[4][4] = {};
  const int nk = DIM / 32;
  for (int k = 0; k < nk; k++) {
    const int cur = (k & 1) * TBUF, nxt = TBUF - cur;
    __syncthreads();
    if (k + 1 < nk) {
      glds16(gA, sA + nxt + lw0);
      glds16(gA + 64l * DIM, sA + nxt + lw1);
      glds16(gB, sB + nxt + lw0);
      glds16(gB + 64l * DIM, sB + nxt + lw1);
      gA += 32; gB += 32;
    }
    f16x8 af[4], bf[4];
#pragma unroll
    for (int mt = 0; mt < 4; mt++)
      af[mt] = *(const f16x8*)(sA + cur + (wm + mt * 16 + lr) * 32 + lk);
#pragma unroll
    for (int nt = 0; nt < 4; nt++)
      bf[nt] = *(const f16x8*)(sB + cur + (wn + nt * 16 + lr) * 32 + lk);
#pragma unroll
    for (int mt = 0; mt < 4; mt++)
#pragma unroll
      for (int nt = 0; nt < 4; nt++)
        acc[mt][nt] = __builtin_amdgcn_mfma_f32_16x16x32_f16(af[mt], bf[nt], acc[mt][nt], 0, 0, 0);
  }

  const int rbase = (l >> 4) * 4;
  f16* C = (sub == 0) ? q_h : (sub == 1) ? k_h : vt_h;
#pragma unroll
  for (int nt = 0; nt < 4; nt++) {
    const long col = bj + wn + nt * 16 + lr;
    const float bb = bias[col];
#pragma unroll
    for (int mt = 0; mt < 4; mt++) {
      const long row0 = bi + wm + mt * 16 + rbase;
      if (sub < 2) {
#pragma unroll
        for (int g = 0; g < 4; g++)
          C[(row0 + g) * DIM + col] = (f16)(acc[mt][nt][g] + bb);
      } else {
        union { unsigned long long u; f16 h[4]; } pk;
#pragma unroll
        for (int g = 0; g < 4; g++) pk.h[g] = (f16)(acc[mt][nt][g] + bb);
        *(unsigned long long*)(C + col * (long)NPTS + row0) = pk.u;
      }
    }
  }
}

// ---------- QK^T: S = exp((q k^T - 50)/2) f16, fused column sum of squares ----------
__global__ __launch_bounds__(256, 2)
void gemm_qk(const f16* __restrict__ A, const f16* __restrict__ B,
             f16* __restrict__ S, float* __restrict__ colsum) {
  __shared__ f16 sA[2 * TBUF];
  __shared__ f16 sB[2 * TBUF];
  const long bi = (long)blockIdx.y * 128;
  const long bj = (long)blockIdx.x * 128;
  const int t = threadIdx.x;
  const int w = t >> 6, l = t & 63;
  const int wm = (w >> 1) * 64, wn = (w & 1) * 64;
  const int lr = l & 15, lk = (l >> 4) * 8;
  const int grow = w * 16 + (l >> 2);
  const int gcol = (l & 3) * 8;
  const f16* gA = A + (bi + grow) * (long)DIM + gcol;
  const f16* gB = B + (bj + grow) * (long)DIM + gcol;
  const int lw0 = (w * 16) * 32, lw1 = (64 + w * 16) * 32;

  glds16(gA, sA + lw0);
  glds16(gA + 64l * DIM, sA + lw1);
  glds16(gB, sB + lw0);
  glds16(gB + 64l * DIM, sB + lw1);
  gA += 32; gB += 32;

  f32x4 acc[4][4] = {};
  const int nk = DIM / 32;
  for (int k = 0; k < nk; k++) {
    const int cur = (k & 1) * TBUF, nxt = TBUF - cur;
    __syncthreads();
    if (k + 1 < nk) {
      glds16(gA, sA + nxt + lw0);
      glds16(gA + 64l * DIM, sA + nxt + lw1);
      glds16(gB, sB + nxt + lw0);
      glds16(gB + 64l * DIM, sB + nxt + lw1);
      gA += 32; gB += 32;
    }
    f16x8 af[4], bf[4];
#pragma unroll
    for (int mt = 0; mt < 4; mt++)
      af[mt] = *(const f16x8*)(sA + cur + (wm + mt * 16 + lr) * 32 + lk);
#pragma unroll
    for (int nt = 0; nt < 4; nt++)
      bf[nt] = *(const f16x8*)(sB + cur + (wn + nt * 16 + lr) * 32 + lk);
#pragma unroll
    for (int mt = 0; mt < 4; mt++)
#pragma unroll
      for (int nt = 0; nt < 4; nt++)
        acc[mt][nt] = __builtin_amdgcn_mfma_f32_16x16x32_f16(af[mt], bf[nt], acc[mt][nt], 0, 0, 0);
  }

  const int rbase = (l >> 4) * 4;
#pragma unroll
  for (int nt = 0; nt < 4; nt++) {
    const long col = bj + wn + nt * 16 + lr;
    float csum = 0.f;
#pragma unroll
    for (int mt = 0; mt < 4; mt++) {
      const long row0 = bi + wm + mt * 16 + rbase;
#pragma unroll
      for (int g = 0; g < 4; g++) {
        float e = exp2f((acc[mt][nt][g] - S2SHIFT) * HL2E);
        e = fminf(e, 240.f);               // e^2 <= 57600 < f16 max; num/denom consistent
        f16 eh = (f16)e;
        S[(row0 + g) * NPTS + col] = eh;
        float ef = (float)eh;
        csum += ef * ef;
      }
    }
    csum += __shfl_xor(csum, 16);
    csum += __shfl_xor(csum, 32);
    if (l < 16) atomicAdd(colsum + col, csum);
  }
}

// ---------- PV split-K: out += P @ v~ ; P staged as (S*ics4)^2 in A path ----------
// grid 2048 = 4 K-splits x 512 swizzled tiles -> ~5 blocks/CU: barrier-drain
// stalls of one block are covered by MFMA issue of the other ~4 (m114 overlap).
__global__ __launch_bounds__(256, 2)
void gemm_pv(const f16* __restrict__ Sm, const f16* __restrict__ vt,
             const f16* __restrict__ ics4, float* __restrict__ out) {
  __shared__ f16 sA[2 * TBUF];
  __shared__ f16 sB[2 * TBUF];
  const int split = blockIdx.x >> 9;
  const int bl_ = blockIdx.x & 511;
  const long bi = (long)(bl_ & 63) * 128;
  const long bj = (long)(bl_ >> 6) * 128;
  const long koff = (long)split * 2048;

  const int t = threadIdx.x;
  const int w = t >> 6, l = t & 63;
  const int wm = (w >> 1) * 64, wn = (w & 1) * 64;
  const int lr = l & 15, lk = (l >> 4) * 8;
  const int grow = w * 16 + (l >> 2);
  const int gcol = (l & 3) * 8;
  const f16* gB = vt + (bj + grow) * (long)NPTS + koff + gcol;
  const int lw0 = (w * 16) * 32, lw1 = (64 + w * 16) * 32;

  // A-side VGPR staging: thread -> row t>>2, chunk t&3
  const int sr = t >> 2, sc = (t & 3) * 8;
  const f16* gAs = Sm + (bi + sr) * (long)NPTS + koff + sc;
  const f16* gIc = ics4 + koff + sc;
  f16x8 ra0, ra1, icv;

  const int nk = 2048 / 32;   // 64 K-steps per split

  // prologue: tile 0 into buffer 0
  ra0 = *(const f16x8*)gAs;
  ra1 = *(const f16x8*)(gAs + 64l * NPTS);
  icv = *(const f16x8*)gIc;
  {
    f16x8 t0 = ra0 * icv; t0 = t0 * t0;   // P = (e * cs^-1/4)^2 = e^2/sqrt(cs)
    f16x8 t1 = ra1 * icv; t1 = t1 * t1;
    *(f16x8*)(sA + sr * 32 + sc) = t0;
    *(f16x8*)(sA + (sr + 64) * 32 + sc) = t1;
  }
  gAs += 32; gIc += 32;
  ra0 = *(const f16x8*)gAs;                // regs for tile 1
  ra1 = *(const f16x8*)(gAs + 64l * NPTS);
  icv = *(const f16x8*)gIc;
  glds16(gB, sB + lw0);
  glds16(gB + 64l * NPTS, sB + lw1);
  gB += 32;

  f32x4 acc[4][4] = {};
  for (int k = 0; k < nk; k++) {
    const int cur = (k & 1) * TBUF, nxt = TBUF - cur;
    __syncthreads();
    if (k + 1 < nk) {
      f16x8 t0 = ra0 * icv; t0 = t0 * t0;
      f16x8 t1 = ra1 * icv; t1 = t1 * t1;
      *(f16x8*)(sA + nxt + sr * 32 + sc) = t0;
      *(f16x8*)(sA + nxt + (sr + 64) * 32 + sc) = t1;
      if (k + 2 < nk) {
        gAs += 32; gIc += 32;
        ra0 = *(const f16x8*)gAs;
        ra1 = *(const f16x8*)(gAs + 64l * NPTS);
        icv = *(const f16x8*)gIc;
      }
      glds16(gB, sB + nxt + lw0);
      glds16(gB + 64l * NPTS, sB + nxt + lw1);
      gB += 32;
    }
    f16x8 af[4], bf[4];
#pragma unroll
    for (int mt = 0; mt < 4; mt++)
      af[mt] = *(const f16x8*)(sA + cur + (wm + mt * 16 + lr) * 32 + lk);
#pragma unroll
    for (int nt = 0; nt < 4; nt++)
      bf[nt] = *(const f16x8*)(sB + cur + (wn + nt * 16 + lr) * 32 + lk);
#pragma unroll
    for (int mt = 0; mt < 4; mt++)
#pragma unroll
      for (int nt = 0; nt < 4; nt++)
        acc[mt][nt] = __builtin_amdgcn_mfma_f32_16x16x32_f16(af[mt], bf[nt], acc[mt][nt], 0, 0, 0);
  }

  const int rbase = (l >> 4) * 4;
#pragma unroll
  for (int nt = 0; nt < 4; nt++) {
    const long col = bj + wn + nt * 16 + lr;
#pragma unroll
    for (int mt = 0; mt < 4; mt++) {
      const long row0 = bi + wm + mt * 16 + rbase;
#pragma unroll
      for (int g = 0; g < 4; g++)
        atomicAdd(out + (row0 + g) * DIM + col, acc[mt][nt][g]);
    }
  }
}

extern "C" void kernel_launch(void* const* d_in, const int* in_sizes, int n_in,
                              void* d_out, int out_size, void* d_ws, size_t ws_size,
                              hipStream_t stream) {
  const float* p  = (const float*)d_in[0];
  const float* r  = (const float*)d_in[1];
  const float* Wh = (const float*)d_in[2];
  const float* bh = (const float*)d_in[3];
  const float* Wl = (const float*)d_in[4];
  const float* bl = (const float*)d_in[5];
  const float* Wg = (const float*)d_in[6];
  const float* bg = (const float*)d_in[7];
  float* out = (float*)d_out;

  char* ws = (char*)d_ws;
  f16* q_h  = (f16*)(ws + (0ull  << 20));
  f16* k_h  = (f16*)(ws + (16ull << 20));
  f16* vt_h = (f16*)(ws + (32ull << 20));   // [D,N] v^T, scaled in place
  f16* p_h  = (f16*)(ws + (48ull << 20));
  f16* r_h  = (f16*)(ws + (64ull << 20));
  f16* wh_h = (f16*)(ws + (80ull << 20));
  f16* wl_h = (f16*)(ws + (82ull << 20));
  f16* wg_h = (f16*)(ws + (84ull << 20));
  f16* S    = (f16*)(ws + (96ull << 20));   // 128 MB: exp((s-50)/2) f16
  float* colsum = (float*)(ws + (224ull << 20));
  f16* ics2 = (f16*)(ws + (225ull << 20));
  f16* ics4 = (f16*)(ws + (226ull << 20));

  const int nP = NPTS * DIM, nW = DIM * DIM;
  cvt_f32_f16<<<nP / 2048, 256, 0, stream>>>(p,  p_h,  nP);
  cvt_f32_f16<<<nP / 2048, 256, 0, stream>>>(r,  r_h,  nP);
  cvt_f32_f16<<<nW / 2048, 256, 0, stream>>>(Wh, wh_h, nW);
  cvt_f32_f16<<<nW / 2048, 256, 0, stream>>>(Wl, wl_h, nW);
  cvt_f32_f16<<<nW / 2048, 256, 0, stream>>>(Wg, wg_h, nW);
  zero_f32<<<NPTS / 256, 256, 0, stream>>>(colsum, NPTS);
  init_out<<<nP / 1024, 256, 0, stream>>>(p, out);   // out = p (residual)

  dim3 blk(256);
  proj_fused<<<1536, blk, 0, stream>>>(p_h, r_h, wh_h, wl_h, wg_h,
                                       bh, bl, bg, q_h, k_h, vt_h);
  gemm_qk<<<dim3(64, 64), blk, 0, stream>>>(q_h, k_h, S, colsum);
  mk_scales<<<NPTS / 256, 256, 0, stream>>>(colsum, ics2, ics4);
  vscale<<<(NPTS / 8) * (DIM / 256), 256, 0, stream>>>(vt_h, ics2);
  gemm_pv<<<2048, blk, 0, stream>>>(S, vt_h, ics4, out);
}

// Round 6
// 583.462 us; speedup vs baseline: 1.0559x; 1.0559x over previous
//
#include <hip/hip_runtime.h>
#include <hip/hip_fp16.h>

typedef _Float16 f16;
typedef __attribute__((ext_vector_type(8))) _Float16 f16x8;
typedef __attribute__((ext_vector_type(4))) float f32x4;

#define NPTS 8192
#define DIM  1024
#define HL2E 0.721347520444482f   // log2(e)/2
#define S2SHIFT 50.0f             // store exp((s-50)/2) in f16
#define TBUF (128 * 32)           // one LDS tile buffer (f16 elems)

// async global->LDS, 16B per lane; lds base must be wave-uniform
__device__ __forceinline__ void glds16(const void* g, void* l) {
  __builtin_amdgcn_global_load_lds(
      (const __attribute__((address_space(1))) void*)g,
      (__attribute__((address_space(3))) void*)l, 16, 0, 0);
}

// LDS chunk swizzle: data chunk kc of row ro lives at slot kc ^ ((ro>>1)&3).
// glds lane fetch column: lane l's LDS slot is (l&3) of row (l>>2) [+w*16,+64],
// so it must FETCH global chunk (l&3)^((l>>3)&3). Frag reads then hit banks
// 2-way max (free, m136) instead of the unpadded layout's 8-way.

// ---------- small helpers ----------
__global__ void cvt_f32_f16(const float* __restrict__ src, f16* __restrict__ dst, int n) {
  int i = (blockIdx.x * 256 + threadIdx.x) * 8;
  if (i >= n) return;
  const float4* s = (const float4*)(src + i);
  float4 a = s[0], b = s[1];
  f16x8 o;
  o[0] = (f16)a.x; o[1] = (f16)a.y; o[2] = (f16)a.z; o[3] = (f16)a.w;
  o[4] = (f16)b.x; o[5] = (f16)b.y; o[6] = (f16)b.z; o[7] = (f16)b.w;
  *(f16x8*)(dst + i) = o;
}

__global__ void zero_f32(float* __restrict__ p, int n) {
  int i = blockIdx.x * 256 + threadIdx.x;
  if (i < n) p[i] = 0.f;
}

// colsum -> ics2 = cs^-1/2 (for v), ics4 = cs^-1/4 (for P staging)
__global__ void mk_scales(const float* __restrict__ colsum,
                          f16* __restrict__ ics2, f16* __restrict__ ics4) {
  int j = blockIdx.x * 256 + threadIdx.x;
  float r2 = rsqrtf(colsum[j]);
  ics2[j] = (f16)r2;
  ics4[j] = (f16)sqrtf(r2);
}

// vt[n][j] *= ics2[j]  (in place, 8-wide packed)
__global__ void vscale(f16* __restrict__ vt, const f16* __restrict__ ics2) {
  long i = ((long)blockIdx.x * 256 + threadIdx.x) * 8;
  f16x8 v = *(f16x8*)(vt + i);
  f16x8 s = *(const f16x8*)(ics2 + (i & (NPTS - 1)));
  *(f16x8*)(vt + i) = v * s;
}

// ---------- fused projections: q = p@Wh^T+bh, k = r@Wl^T+bl, vt = (p@Wg^T+bg)^T ----------
__global__ __launch_bounds__(256, 2)
void proj_fused(const f16* __restrict__ p_h, const f16* __restrict__ r_h,
                const f16* __restrict__ Wh, const f16* __restrict__ Wl,
                const f16* __restrict__ Wg,
                const float* __restrict__ bh, const float* __restrict__ bl,
                const float* __restrict__ bg,
                f16* __restrict__ q_h, f16* __restrict__ k_h,
                f16* __restrict__ vt_h) {
  __shared__ f16 sA[2 * TBUF];
  __shared__ f16 sB[2 * TBUF];
  const int sub = blockIdx.x >> 9;
  const int bl_ = blockIdx.x & 511;
  const long bi = (long)(bl_ & 63) * 128;
  const long bj = (long)(bl_ >> 6) * 128;
  const f16* A = (sub == 1) ? r_h : p_h;
  const f16* B = (sub == 0) ? Wh : (sub == 1) ? Wl : Wg;
  const float* bias = (sub == 0) ? bh : (sub == 1) ? bl : bg;

  const int t = threadIdx.x;
  const int w = t >> 6, l = t & 63;
  const int wm = (w >> 1) * 64, wn = (w & 1) * 64;
  const int lr = l & 15;
  // swizzled frag-read base (per-lane constant; 2-way banks max)
  const int fbase = lr * 32 + (((l >> 4) ^ ((lr >> 1) & 3)) * 8);
  const int grow = w * 16 + (l >> 2);
  const int gcol = ((l & 3) ^ ((l >> 3) & 3)) * 8;   // swizzled fetch column
  const f16* gA = A + (bi + grow) * (long)DIM + gcol;
  const f16* gB = B + (bj + grow) * (long)DIM + gcol;
  const int lw0 = (w * 16) * 32, lw1 = (64 + w * 16) * 32;

  glds16(gA, sA + lw0);
  glds16(gA + 64l * DIM, sA + lw1);
  glds16(gB, sB + lw0);
  glds16(gB + 64l * DIM, sB + lw1);
  gA += 32; gB += 32;

  f32x4 acc[4][4] = {};
  const int nk = DIM / 32;
  for (int k = 0; k < nk; k++) {
    const int cur = (k & 1) * TBUF, nxt = TBUF - cur;
    __syncthreads();
    if (k + 1 < nk) {
      glds16(gA, sA + nxt + lw0);
      glds16(gA + 64l * DIM, sA + nxt + lw1);
      glds16(gB, sB + nxt + lw0);
      glds16(gB + 64l * DIM, sB + nxt + lw1);
      gA += 32; gB += 32;
    }
    f16x8 af[4], bf[4];
#pragma unroll
    for (int mt = 0; mt < 4; mt++)
      af[mt] = *(const f16x8*)(sA + cur + (wm + mt * 16) * 32 + fbase);
#pragma unroll
    for (int nt = 0; nt < 4; nt++)
      bf[nt] = *(const f16x8*)(sB + cur + (wn + nt * 16) * 32 + fbase);
#pragma unroll
    for (int mt = 0; mt < 4; mt++)
#pragma unroll
      for (int nt = 0; nt < 4; nt++)
        acc[mt][nt] = __builtin_amdgcn_mfma_f32_16x16x32_f16(af[mt], bf[nt], acc[mt][nt], 0, 0, 0);
  }

  const int rbase = (l >> 4) * 4;
  f16* C = (sub == 0) ? q_h : (sub == 1) ? k_h : vt_h;
#pragma unroll
  for (int nt = 0; nt < 4; nt++) {
    const long col = bj + wn + nt * 16 + lr;
    const float bb = bias[col];
#pragma unroll
    for (int mt = 0; mt < 4; mt++) {
      const long row0 = bi + wm + mt * 16 + rbase;
      if (sub < 2) {
#pragma unroll
        for (int g = 0; g < 4; g++)
          C[(row0 + g) * DIM + col] = (f16)(acc[mt][nt][g] + bb);
      } else {
        union { unsigned long long u; f16 h[4]; } pk;
#pragma unroll
        for (int g = 0; g < 4; g++) pk.h[g] = (f16)(acc[mt][nt][g] + bb);
        *(unsigned long long*)(C + col * (long)NPTS + row0) = pk.u;
      }
    }
  }
}

// ---------- QK^T: S = exp((q k^T - 50)/2) f16, fused column sum of squares ----------
__global__ __launch_bounds__(256, 2)
void gemm_qk(const f16* __restrict__ A, const f16* __restrict__ B,
             f16* __restrict__ S, float* __restrict__ colsum) {
  __shared__ f16 sA[2 * TBUF];
  __shared__ f16 sB[2 * TBUF];
  const long bi = (long)blockIdx.y * 128;
  const long bj = (long)blockIdx.x * 128;
  const int t = threadIdx.x;
  const int w = t >> 6, l = t & 63;
  const int wm = (w >> 1) * 64, wn = (w & 1) * 64;
  const int lr = l & 15;
  const int fbase = lr * 32 + (((l >> 4) ^ ((lr >> 1) & 3)) * 8);
  const int grow = w * 16 + (l >> 2);
  const int gcol = ((l & 3) ^ ((l >> 3) & 3)) * 8;
  const f16* gA = A + (bi + grow) * (long)DIM + gcol;
  const f16* gB = B + (bj + grow) * (long)DIM + gcol;
  const int lw0 = (w * 16) * 32, lw1 = (64 + w * 16) * 32;

  glds16(gA, sA + lw0);
  glds16(gA + 64l * DIM, sA + lw1);
  glds16(gB, sB + lw0);
  glds16(gB + 64l * DIM, sB + lw1);
  gA += 32; gB += 32;

  f32x4 acc[4][4] = {};
  const int nk = DIM / 32;
  for (int k = 0; k < nk; k++) {
    const int cur = (k & 1) * TBUF, nxt = TBUF - cur;
    __syncthreads();
    if (k + 1 < nk) {
      glds16(gA, sA + nxt + lw0);
      glds16(gA + 64l * DIM, sA + nxt + lw1);
      glds16(gB, sB + nxt + lw0);
      glds16(gB + 64l * DIM, sB + nxt + lw1);
      gA += 32; gB += 32;
    }
    f16x8 af[4], bf[4];
#pragma unroll
    for (int mt = 0; mt < 4; mt++)
      af[mt] = *(const f16x8*)(sA + cur + (wm + mt * 16) * 32 + fbase);
#pragma unroll
    for (int nt = 0; nt < 4; nt++)
      bf[nt] = *(const f16x8*)(sB + cur + (wn + nt * 16) * 32 + fbase);
#pragma unroll
    for (int mt = 0; mt < 4; mt++)
#pragma unroll
      for (int nt = 0; nt < 4; nt++)
        acc[mt][nt] = __builtin_amdgcn_mfma_f32_16x16x32_f16(af[mt], bf[nt], acc[mt][nt], 0, 0, 0);
  }

  const int rbase = (l >> 4) * 4;
#pragma unroll
  for (int nt = 0; nt < 4; nt++) {
    const long col = bj + wn + nt * 16 + lr;
    float csum = 0.f;
#pragma unroll
    for (int mt = 0; mt < 4; mt++) {
      const long row0 = bi + wm + mt * 16 + rbase;
#pragma unroll
      for (int g = 0; g < 4; g++) {
        float e = exp2f((acc[mt][nt][g] - S2SHIFT) * HL2E);
        e = fminf(e, 240.f);               // e^2 <= 57600 < f16 max; num/denom consistent
        f16 eh = (f16)e;
        S[(row0 + g) * NPTS + col] = eh;
        float ef = (float)eh;
        csum += ef * ef;
      }
    }
    csum += __shfl_xor(csum, 16);
    csum += __shfl_xor(csum, 32);
    if (l < 16) atomicAdd(colsum + col, csum);
  }
}

// ---------- PV: out = P @ v~ + p ; P staged as (S*ics4)^2 in A path ----------
// 512-block swizzled grid (bi = b&63 -> XCD round-robin; S row-panel L2-hit 7/8)
__global__ __launch_bounds__(256, 2)
void gemm_pv(const f16* __restrict__ Sm, const f16* __restrict__ vt,
             const f16* __restrict__ ics4, const float* __restrict__ Res,
             float* __restrict__ out) {
  __shared__ f16 sA[2 * TBUF];
  __shared__ f16 sB[2 * TBUF];
  const long bi = (long)(blockIdx.x & 63) * 128;
  const long bj = (long)(blockIdx.x >> 6) * 128;

  const int t = threadIdx.x;
  const int w = t >> 6, l = t & 63;
  const int wm = (w >> 1) * 64, wn = (w & 1) * 64;
  const int lr = l & 15;
  const int fbase = lr * 32 + (((l >> 4) ^ ((lr >> 1) & 3)) * 8);
  const int grow = w * 16 + (l >> 2);
  const int gcol = ((l & 3) ^ ((l >> 3) & 3)) * 8;
  const f16* gB = vt + (bj + grow) * (long)NPTS + gcol;
  const int lw0 = (w * 16) * 32, lw1 = (64 + w * 16) * 32;

  // A-side VGPR staging: thread -> row t>>2 (+64), global chunk t&3,
  // swizzled LDS slot (t&3)^((t>>3)&3)
  const int sr = t >> 2, sc = (t & 3) * 8;
  const int ssw = ((t & 3) ^ ((t >> 3) & 3)) * 8;
  const f16* gAs = Sm + (bi + sr) * (long)NPTS + sc;
  const f16* gIc = ics4 + sc;
  f16x8 ra0, ra1, icv;

  const int nk = NPTS / 32;

  // prologue: tile 0 into buffer 0
  ra0 = *(const f16x8*)gAs;
  ra1 = *(const f16x8*)(gAs + 64l * NPTS);
  icv = *(const f16x8*)gIc;
  {
    f16x8 t0 = ra0 * icv; t0 = t0 * t0;   // P = (e * cs^-1/4)^2 = e^2/sqrt(cs)
    f16x8 t1 = ra1 * icv; t1 = t1 * t1;
    *(f16x8*)(sA + sr * 32 + ssw) = t0;
    *(f16x8*)(sA + (sr + 64) * 32 + ssw) = t1;
  }
  gAs += 32; gIc += 32;
  ra0 = *(const f16x8*)gAs;                // regs for tile 1
  ra1 = *(const f16x8*)(gAs + 64l * NPTS);
  icv = *(const f16x8*)gIc;
  glds16(gB, sB + lw0);
  glds16(gB + 64l * NPTS, sB + lw1);
  gB += 32;

  f32x4 acc[4][4] = {};
  for (int k = 0; k < nk; k++) {
    const int cur = (k & 1) * TBUF, nxt = TBUF - cur;
    __syncthreads();
    if (k + 1 < nk) {
      f16x8 t0 = ra0 * icv; t0 = t0 * t0;
      f16x8 t1 = ra1 * icv; t1 = t1 * t1;
      *(f16x8*)(sA + nxt + sr * 32 + ssw) = t0;
      *(f16x8*)(sA + nxt + (sr + 64) * 32 + ssw) = t1;
      if (k + 2 < nk) {
        gAs += 32; gIc += 32;
        ra0 = *(const f16x8*)gAs;
        ra1 = *(const f16x8*)(gAs + 64l * NPTS);
        icv = *(const f16x8*)gIc;
      }
      glds16(gB, sB + nxt + lw0);
      glds16(gB + 64l * NPTS, sB + nxt + lw1);
      gB += 32;
    }
    f16x8 af[4], bf[4];
#pragma unroll
    for (int mt = 0; mt < 4; mt++)
      af[mt] = *(const f16x8*)(sA + cur + (wm + mt * 16) * 32 + fbase);
#pragma unroll
    for (int nt = 0; nt < 4; nt++)
      bf[nt] = *(const f16x8*)(sB + cur + (wn + nt * 16) * 32 + fbase);
#pragma unroll
    for (int mt = 0; mt < 4; mt++)
#pragma unroll
      for (int nt = 0; nt < 4; nt++)
        acc[mt][nt] = __builtin_amdgcn_mfma_f32_16x16x32_f16(af[mt], bf[nt], acc[mt][nt], 0, 0, 0);
  }

  const int rbase = (l >> 4) * 4;
#pragma unroll
  for (int nt = 0; nt < 4; nt++) {
    const long col = bj + wn + nt * 16 + lr;
#pragma unroll
    for (int mt = 0; mt < 4; mt++) {
      const long row0 = bi + wm + mt * 16 + rbase;
#pragma unroll
      for (int g = 0; g < 4; g++)
        out[(row0 + g) * DIM + col] = acc[mt][nt][g] + Res[(row0 + g) * (long)DIM + col];
    }
  }
}

extern "C" void kernel_launch(void* const* d_in, const int* in_sizes, int n_in,
                              void* d_out, int out_size, void* d_ws, size_t ws_size,
                              hipStream_t stream) {
  const float* p  = (const float*)d_in[0];
  const float* r  = (const float*)d_in[1];
  const float* Wh = (const float*)d_in[2];
  const float* bh = (const float*)d_in[3];
  const float* Wl = (const float*)d_in[4];
  const float* bl = (const float*)d_in[5];
  const float* Wg = (const float*)d_in[6];
  const float* bg = (const float*)d_in[7];
  float* out = (float*)d_out;

  char* ws = (char*)d_ws;
  f16* q_h  = (f16*)(ws + (0ull  << 20));
  f16* k_h  = (f16*)(ws + (16ull << 20));
  f16* vt_h = (f16*)(ws + (32ull << 20));   // [D,N] v^T, scaled in place
  f16* p_h  = (f16*)(ws + (48ull << 20));
  f16* r_h  = (f16*)(ws + (64ull << 20));
  f16* wh_h = (f16*)(ws + (80ull << 20));
  f16* wl_h = (f16*)(ws + (82ull << 20));
  f16* wg_h = (f16*)(ws + (84ull << 20));
  f16* S    = (f16*)(ws + (96ull << 20));   // 128 MB: exp((s-50)/2) f16
  float* colsum = (float*)(ws + (224ull << 20));
  f16* ics2 = (f16*)(ws + (225ull << 20));
  f16* ics4 = (f16*)(ws + (226ull << 20));

  const int nP = NPTS * DIM, nW = DIM * DIM;
  cvt_f32_f16<<<nP / 2048, 256, 0, stream>>>(p,  p_h,  nP);
  cvt_f32_f16<<<nP / 2048, 256, 0, stream>>>(r,  r_h,  nP);
  cvt_f32_f16<<<nW / 2048, 256, 0, stream>>>(Wh, wh_h, nW);
  cvt_f32_f16<<<nW / 2048, 256, 0, stream>>>(Wl, wl_h, nW);
  cvt_f32_f16<<<nW / 2048, 256, 0, stream>>>(Wg, wg_h, nW);
  zero_f32<<<NPTS / 256, 256, 0, stream>>>(colsum, NPTS);

  dim3 blk(256);
  proj_fused<<<1536, blk, 0, stream>>>(p_h, r_h, wh_h, wl_h, wg_h,
                                       bh, bl, bg, q_h, k_h, vt_h);
  gemm_qk<<<dim3(64, 64), blk, 0, stream>>>(q_h, k_h, S, colsum);
  mk_scales<<<NPTS / 256, 256, 0, stream>>>(colsum, ics2, ics4);
  vscale<<<(NPTS / 8) * (DIM / 256), 256, 0, stream>>>(vt_h, ics2);
  gemm_pv<<<512, blk, 0, stream>>>(S, vt_h, ics4, p, out);
}

// Round 7
// 540.737 us; speedup vs baseline: 1.1393x; 1.0790x over previous
//
#include <hip/hip_runtime.h>
#include <hip/hip_fp16.h>

typedef _Float16 f16;
typedef __attribute__((ext_vector_type(8))) _Float16 f16x8;
typedef __attribute__((ext_vector_type(4))) float f32x4;

#define NPTS 8192
#define DIM  1024
#define HL2E 0.721347520444482f   // log2(e)/2
#define S2SHIFT 50.0f             // store exp((s-50)/2) in f16
#define TBUF (128 * 32)           // one LDS tile buffer (f16 elems)

// async global->LDS, 16B per lane; lds base must be wave-uniform
__device__ __forceinline__ void glds16(const void* g, void* l) {
  __builtin_amdgcn_global_load_lds(
      (const __attribute__((address_space(1))) void*)g,
      (__attribute__((address_space(3))) void*)l, 16, 0, 0);
}

// LDS chunk swizzle (kept from R6: conflicts 1.7e7 -> 0): data chunk kc of row
// ro lives at slot kc ^ ((ro>>1)&3); glds lanes fetch global chunk
// (l&3)^((l>>3)&3); frag reads use per-lane base with the same XOR.

// ---------- small helpers ----------
__global__ void cvt_f32_f16(const float* __restrict__ src, f16* __restrict__ dst, int n) {
  int i = (blockIdx.x * 256 + threadIdx.x) * 8;
  if (i >= n) return;
  const float4* s = (const float4*)(src + i);
  float4 a = s[0], b = s[1];
  f16x8 o;
  o[0] = (f16)a.x; o[1] = (f16)a.y; o[2] = (f16)a.z; o[3] = (f16)a.w;
  o[4] = (f16)b.x; o[5] = (f16)b.y; o[6] = (f16)b.z; o[7] = (f16)b.w;
  *(f16x8*)(dst + i) = o;
}

__global__ void zero_f32(float* __restrict__ p, int n) {
  int i = blockIdx.x * 256 + threadIdx.x;
  if (i < n) p[i] = 0.f;
}

// colsum -> ics2 = cs^-1/2 (for v), ics4 = cs^-1/4 (for P staging)
__global__ void mk_scales(const float* __restrict__ colsum,
                          f16* __restrict__ ics2, f16* __restrict__ ics4) {
  int j = blockIdx.x * 256 + threadIdx.x;
  float r2 = rsqrtf(colsum[j]);
  ics2[j] = (f16)r2;
  ics4[j] = (f16)sqrtf(r2);
}

// vt[n][j] *= ics2[j]  (in place, 8-wide packed)
__global__ void vscale(f16* __restrict__ vt, const f16* __restrict__ ics2) {
  long i = ((long)blockIdx.x * 256 + threadIdx.x) * 8;
  f16x8 v = *(f16x8*)(vt + i);
  f16x8 s = *(const f16x8*)(ics2 + (i & (NPTS - 1)));
  *(f16x8*)(vt + i) = v * s;
}

// out = p + part0 + part1  (PV split-K combine + residual)
__global__ void reduce_out(const float* __restrict__ p,
                           const float* __restrict__ pa,
                           const float* __restrict__ pb,
                           float* __restrict__ out) {
  long i = ((long)blockIdx.x * 256 + threadIdx.x) * 4;
  float4 a = *(const float4*)(p + i);
  float4 b = *(const float4*)(pa + i);
  float4 c = *(const float4*)(pb + i);
  a.x += b.x + c.x; a.y += b.y + c.y; a.z += b.z + c.z; a.w += b.w + c.w;
  *(float4*)(out + i) = a;
}

// ---------- fused projections: q = p@Wh^T+bh, k = r@Wl^T+bl, vt = (p@Wg^T+bg)^T ----------
__global__ __launch_bounds__(256, 2)
void proj_fused(const f16* __restrict__ p_h, const f16* __restrict__ r_h,
                const f16* __restrict__ Wh, const f16* __restrict__ Wl,
                const f16* __restrict__ Wg,
                const float* __restrict__ bh, const float* __restrict__ bl,
                const float* __restrict__ bg,
                f16* __restrict__ q_h, f16* __restrict__ k_h,
                f16* __restrict__ vt_h) {
  __shared__ f16 sA[2 * TBUF];
  __shared__ f16 sB[2 * TBUF];
  const int sub = blockIdx.x >> 9;
  const int bl_ = blockIdx.x & 511;
  const long bi = (long)(bl_ & 63) * 128;
  const long bj = (long)(bl_ >> 6) * 128;
  const f16* A = (sub == 1) ? r_h : p_h;
  const f16* B = (sub == 0) ? Wh : (sub == 1) ? Wl : Wg;
  const float* bias = (sub == 0) ? bh : (sub == 1) ? bl : bg;

  const int t = threadIdx.x;
  const int w = t >> 6, l = t & 63;
  const int wm = (w >> 1) * 64, wn = (w & 1) * 64;
  const int lr = l & 15;
  const int fbase = lr * 32 + (((l >> 4) ^ ((lr >> 1) & 3)) * 8);
  const int grow = w * 16 + (l >> 2);
  const int gcol = ((l & 3) ^ ((l >> 3) & 3)) * 8;
  const f16* gA = A + (bi + grow) * (long)DIM + gcol;
  const f16* gB = B + (bj + grow) * (long)DIM + gcol;
  const int lw0 = (w * 16) * 32, lw1 = (64 + w * 16) * 32;

  glds16(gA, sA + lw0);
  glds16(gA + 64l * DIM, sA + lw1);
  glds16(gB, sB + lw0);
  glds16(gB + 64l * DIM, sB + lw1);
  gA += 32; gB += 32;

  f32x4 acc[4][4] = {};
  const int nk = DIM / 32;
  for (int k = 0; k < nk; k++) {
    const int cur = (k & 1) * TBUF, nxt = TBUF - cur;
    __syncthreads();
    if (k + 1 < nk) {
      glds16(gA, sA + nxt + lw0);
      glds16(gA + 64l * DIM, sA + nxt + lw1);
      glds16(gB, sB + nxt + lw0);
      glds16(gB + 64l * DIM, sB + nxt + lw1);
      gA += 32; gB += 32;
    }
    f16x8 af[4], bf[4];
#pragma unroll
    for (int mt = 0; mt < 4; mt++)
      af[mt] = *(const f16x8*)(sA + cur + (wm + mt * 16) * 32 + fbase);
#pragma unroll
    for (int nt = 0; nt < 4; nt++)
      bf[nt] = *(const f16x8*)(sB + cur + (wn + nt * 16) * 32 + fbase);
#pragma unroll
    for (int mt = 0; mt < 4; mt++)
#pragma unroll
      for (int nt = 0; nt < 4; nt++)
        acc[mt][nt] = __builtin_amdgcn_mfma_f32_16x16x32_f16(af[mt], bf[nt], acc[mt][nt], 0, 0, 0);
  }

  const int rbase = (l >> 4) * 4;
  f16* C = (sub == 0) ? q_h : (sub == 1) ? k_h : vt_h;
#pragma unroll
  for (int nt = 0; nt < 4; nt++) {
    const long col = bj + wn + nt * 16 + lr;
    const float bb = bias[col];
#pragma unroll
    for (int mt = 0; mt < 4; mt++) {
      const long row0 = bi + wm + mt * 16 + rbase;
      if (sub < 2) {
#pragma unroll
        for (int g = 0; g < 4; g++)
          C[(row0 + g) * DIM + col] = (f16)(acc[mt][nt][g] + bb);
      } else {
        union { unsigned long long u; f16 h[4]; } pk;
#pragma unroll
        for (int g = 0; g < 4; g++) pk.h[g] = (f16)(acc[mt][nt][g] + bb);
        *(unsigned long long*)(C + col * (long)NPTS + row0) = pk.u;
      }
    }
  }
}

// ---------- QK^T: S = exp((q k^T - 50)/2) f16, fused column sum of squares ----------
// XCD column-strip swizzle: sx = b&7 (dispatch round-robins XCDs) pins each XCD
// to col-blocks [sx*8, sx*8+8) -> its 8 k-panels (2 MB) stay resident in that
// XCD's L2 for the whole kernel; q-panels stream through L3.
__global__ __launch_bounds__(256, 2)
void gemm_qk(const f16* __restrict__ A, const f16* __restrict__ B,
             f16* __restrict__ S, float* __restrict__ colsum) {
  __shared__ f16 sA[2 * TBUF];
  __shared__ f16 sB[2 * TBUF];
  const int b = blockIdx.x;
  const int sx = b & 7;            // XCD id
  const int j = b >> 3;            // 0..511 within XCD
  const int st = j >> 6;           // 0..7 row super-group
  const int wi = j & 63;
  const long bi = (long)(st * 8 + (wi >> 3)) * 128;
  const long bj = (long)(sx * 8 + (wi & 7)) * 128;
  const int t = threadIdx.x;
  const int w = t >> 6, l = t & 63;
  const int wm = (w >> 1) * 64, wn = (w & 1) * 64;
  const int lr = l & 15;
  const int fbase = lr * 32 + (((l >> 4) ^ ((lr >> 1) & 3)) * 8);
  const int grow = w * 16 + (l >> 2);
  const int gcol = ((l & 3) ^ ((l >> 3) & 3)) * 8;
  const f16* gA = A + (bi + grow) * (long)DIM + gcol;
  const f16* gB = B + (bj + grow) * (long)DIM + gcol;
  const int lw0 = (w * 16) * 32, lw1 = (64 + w * 16) * 32;

  glds16(gA, sA + lw0);
  glds16(gA + 64l * DIM, sA + lw1);
  glds16(gB, sB + lw0);
  glds16(gB + 64l * DIM, sB + lw1);
  gA += 32; gB += 32;

  f32x4 acc[4][4] = {};
  const int nk = DIM / 32;
  for (int k = 0; k < nk; k++) {
    const int cur = (k & 1) * TBUF, nxt = TBUF - cur;
    __syncthreads();
    if (k + 1 < nk) {
      glds16(gA, sA + nxt + lw0);
      glds16(gA + 64l * DIM, sA + nxt + lw1);
      glds16(gB, sB + nxt + lw0);
      glds16(gB + 64l * DIM, sB + nxt + lw1);
      gA += 32; gB += 32;
    }
    f16x8 af[4], bf[4];
#pragma unroll
    for (int mt = 0; mt < 4; mt++)
      af[mt] = *(const f16x8*)(sA + cur + (wm + mt * 16) * 32 + fbase);
#pragma unroll
    for (int nt = 0; nt < 4; nt++)
      bf[nt] = *(const f16x8*)(sB + cur + (wn + nt * 16) * 32 + fbase);
#pragma unroll
    for (int mt = 0; mt < 4; mt++)
#pragma unroll
      for (int nt = 0; nt < 4; nt++)
        acc[mt][nt] = __builtin_amdgcn_mfma_f32_16x16x32_f16(af[mt], bf[nt], acc[mt][nt], 0, 0, 0);
  }

  const int rbase = (l >> 4) * 4;
#pragma unroll
  for (int nt = 0; nt < 4; nt++) {
    const long col = bj + wn + nt * 16 + lr;
    float csum = 0.f;
#pragma unroll
    for (int mt = 0; mt < 4; mt++) {
      const long row0 = bi + wm + mt * 16 + rbase;
#pragma unroll
      for (int g = 0; g < 4; g++) {
        float e = exp2f((acc[mt][nt][g] - S2SHIFT) * HL2E);
        e = fminf(e, 240.f);               // e^2 <= 57600 < f16 max; num/denom consistent
        f16 eh = (f16)e;
        S[(row0 + g) * NPTS + col] = eh;
        float ef = (float)eh;
        csum += ef * ef;
      }
    }
    csum += __shfl_xor(csum, 16);
    csum += __shfl_xor(csum, 32);
    if (l < 16) atomicAdd(colsum + col, csum);
  }
}

// ---------- PV split-K x2: part[s] = P[:, sK/2:(s+1)K/2] @ v~[...] ----------
// grid 1024 = 2 K-splits x 512 swizzled tiles -> 4 blocks/CU feeds the LDS pipe
// through barrier drains/tails. Partials are PRIVATE buffers (no atomic RMW);
// reduce_out combines. bi = b&63 keeps the 8-col-tiles-per-XCD S L2 reuse.
__global__ __launch_bounds__(256, 2)
void gemm_pv(const f16* __restrict__ Sm, const f16* __restrict__ vt,
             const f16* __restrict__ ics4,
             float* __restrict__ part0, float* __restrict__ part1) {
  __shared__ f16 sA[2 * TBUF];
  __shared__ f16 sB[2 * TBUF];
  const int split = blockIdx.x >> 9;
  const int bl_ = blockIdx.x & 511;
  const long bi = (long)(bl_ & 63) * 128;
  const long bj = (long)(bl_ >> 6) * 128;
  const long koff = (long)split * (NPTS / 2);

  const int t = threadIdx.x;
  const int w = t >> 6, l = t & 63;
  const int wm = (w >> 1) * 64, wn = (w & 1) * 64;
  const int lr = l & 15;
  const int fbase = lr * 32 + (((l >> 4) ^ ((lr >> 1) & 3)) * 8);
  const int grow = w * 16 + (l >> 2);
  const int gcol = ((l & 3) ^ ((l >> 3) & 3)) * 8;
  const f16* gB = vt + (bj + grow) * (long)NPTS + koff + gcol;
  const int lw0 = (w * 16) * 32, lw1 = (64 + w * 16) * 32;

  // A-side VGPR staging: thread -> row t>>2 (+64), global chunk t&3,
  // swizzled LDS slot (t&3)^((t>>3)&3)
  const int sr = t >> 2, sc = (t & 3) * 8;
  const int ssw = ((t & 3) ^ ((t >> 3) & 3)) * 8;
  const f16* gAs = Sm + (bi + sr) * (long)NPTS + koff + sc;
  const f16* gIc = ics4 + koff + sc;
  f16x8 ra0, ra1, icv;

  const int nk = (NPTS / 2) / 32;   // 128 K-steps per split

  // prologue: tile 0 into buffer 0
  ra0 = *(const f16x8*)gAs;
  ra1 = *(const f16x8*)(gAs + 64l * NPTS);
  icv = *(const f16x8*)gIc;
  {
    f16x8 t0 = ra0 * icv; t0 = t0 * t0;   // P = (e * cs^-1/4)^2 = e^2/sqrt(cs)
    f16x8 t1 = ra1 * icv; t1 = t1 * t1;
    *(f16x8*)(sA + sr * 32 + ssw) = t0;
    *(f16x8*)(sA + (sr + 64) * 32 + ssw) = t1;
  }
  gAs += 32; gIc += 32;
  ra0 = *(const f16x8*)gAs;                // regs for tile 1
  ra1 = *(const f16x8*)(gAs + 64l * NPTS);
  icv = *(const f16x8*)gIc;
  glds16(gB, sB + lw0);
  glds16(gB + 64l * NPTS, sB + lw1);
  gB += 32;

  f32x4 acc[4][4] = {};
  for (int k = 0; k < nk; k++) {
    const int cur = (k & 1) * TBUF, nxt = TBUF - cur;
    __syncthreads();
    if (k + 1 < nk) {
      f16x8 t0 = ra0 * icv; t0 = t0 * t0;
      f16x8 t1 = ra1 * icv; t1 = t1 * t1;
      *(f16x8*)(sA + nxt + sr * 32 + ssw) = t0;
      *(f16x8*)(sA + nxt + (sr + 64) * 32 + ssw) = t1;
      if (k + 2 < nk) {
        gAs += 32; gIc += 32;
        ra0 = *(const f16x8*)gAs;
        ra1 = *(const f16x8*)(gAs + 64l * NPTS);
        icv = *(const f16x8*)gIc;
      }
      glds16(gB, sB + nxt + lw0);
      glds16(gB + 64l * NPTS, sB + nxt + lw1);
      gB += 32;
    }
    f16x8 af[4], bf[4];
#pragma unroll
    for (int mt = 0; mt < 4; mt++)
      af[mt] = *(const f16x8*)(sA + cur + (wm + mt * 16) * 32 + fbase);
#pragma unroll
    for (int nt = 0; nt < 4; nt++)
      bf[nt] = *(const f16x8*)(sB + cur + (wn + nt * 16) * 32 + fbase);
#pragma unroll
    for (int mt = 0; mt < 4; mt++)
#pragma unroll
      for (int nt = 0; nt < 4; nt++)
        acc[mt][nt] = __builtin_amdgcn_mfma_f32_16x16x32_f16(af[mt], bf[nt], acc[mt][nt], 0, 0, 0);
  }

  float* part = split ? part1 : part0;
  const int rbase = (l >> 4) * 4;
#pragma unroll
  for (int nt = 0; nt < 4; nt++) {
    const long col = bj + wn + nt * 16 + lr;
#pragma unroll
    for (int mt = 0; mt < 4; mt++) {
      const long row0 = bi + wm + mt * 16 + rbase;
#pragma unroll
      for (int g = 0; g < 4; g++)
        part[(row0 + g) * DIM + col] = acc[mt][nt][g];
    }
  }
}

extern "C" void kernel_launch(void* const* d_in, const int* in_sizes, int n_in,
                              void* d_out, int out_size, void* d_ws, size_t ws_size,
                              hipStream_t stream) {
  const float* p  = (const float*)d_in[0];
  const float* r  = (const float*)d_in[1];
  const float* Wh = (const float*)d_in[2];
  const float* bh = (const float*)d_in[3];
  const float* Wl = (const float*)d_in[4];
  const float* bl = (const float*)d_in[5];
  const float* Wg = (const float*)d_in[6];
  const float* bg = (const float*)d_in[7];
  float* out = (float*)d_out;

  char* ws = (char*)d_ws;
  f16* q_h  = (f16*)(ws + (0ull  << 20));
  f16* k_h  = (f16*)(ws + (16ull << 20));
  f16* vt_h = (f16*)(ws + (32ull << 20));   // [D,N] v^T, scaled in place
  f16* p_h  = (f16*)(ws + (48ull << 20));
  f16* r_h  = (f16*)(ws + (64ull << 20));
  f16* wh_h = (f16*)(ws + (80ull << 20));
  f16* wl_h = (f16*)(ws + (82ull << 20));
  f16* wg_h = (f16*)(ws + (84ull << 20));
  f16* S    = (f16*)(ws + (96ull << 20));   // 128 MB: exp((s-50)/2) f16
  float* colsum = (float*)(ws + (224ull << 20));
  f16* ics2 = (f16*)(ws + (225ull << 20));
  f16* ics4 = (f16*)(ws + (226ull << 20));
  // PV partials overlay regions dead after QK: q_h/k_h and p_h/r_h (32 MB each)
  float* part0 = (float*)(ws + (0ull  << 20));
  float* part1 = (float*)(ws + (48ull << 20));

  const int nP = NPTS * DIM, nW = DIM * DIM;
  cvt_f32_f16<<<nP / 2048, 256, 0, stream>>>(p,  p_h,  nP);
  cvt_f32_f16<<<nP / 2048, 256, 0, stream>>>(r,  r_h,  nP);
  cvt_f32_f16<<<nW / 2048, 256, 0, stream>>>(Wh, wh_h, nW);
  cvt_f32_f16<<<nW / 2048, 256, 0, stream>>>(Wl, wl_h, nW);
  cvt_f32_f16<<<nW / 2048, 256, 0, stream>>>(Wg, wg_h, nW);
  zero_f32<<<NPTS / 256, 256, 0, stream>>>(colsum, NPTS);

  dim3 blk(256);
  proj_fused<<<1536, blk, 0, stream>>>(p_h, r_h, wh_h, wl_h, wg_h,
                                       bh, bl, bg, q_h, k_h, vt_h);
  gemm_qk<<<4096, blk, 0, stream>>>(q_h, k_h, S, colsum);
  mk_scales<<<NPTS / 256, 256, 0, stream>>>(colsum, ics2, ics4);
  vscale<<<(NPTS / 8) * (DIM / 256), 256, 0, stream>>>(vt_h, ics2);
  gemm_pv<<<1024, blk, 0, stream>>>(S, vt_h, ics4, part0, part1);
  reduce_out<<<nP / 1024, 256, 0, stream>>>(p, part0, part1, out);
}